// Round 3
// baseline (1118.022 us; speedup 1.0000x reference)
//
#include <hip/hip_runtime.h>
#include <cfloat>
#include <math.h>

// Problem constants
#define BQ 8
#define T 2048
#define D 256
#define DAC 36
#define CH 292
#define K 8192
#define NROWS (BQ*T)          // 16384
#define NSPLIT 4
#define MT 32                 // rows per block (exact GEMM)
#define KT 128                // k per tile
#define DC 32                 // d chunk

// Output offsets (floats, reference return order)
#define OFF_IDX   (BQ*CH*T)                 // after z_out
#define OFF_CODES (OFF_IDX + NROWS)         // after indices
#define OFF_LOSS  (OFF_CODES + BQ*DAC*T)    // after ac_codes
#define OFF_ACQ   (OFF_LOSS + 1)            // after vq_loss scalar

// Workspace offsets (bytes)
#define WS_C2    0                          // float[K]
#define WS_Z2    32768                      // float[NROWS]
#define WS_PART  131072                     // float2[NROWS*NSPLIT] = 512KB
#define WS_IDX   655360                     // int[NROWS]
#define WS_LOSS  720896                     // double[512]

// ---- numpy pairwise-sum emulation (AVX512 W=16, n=256 -> two 128 blocks) ----
// per 128-block: r_j = 16-lane chunk j (j=0..7); lanewise tree
// v = ((r0+r1)+(r2+r3))+((r4+r5)+(r6+r7)); then GCC _mm512_reduce_add_ps tree.
template <typename F>
__device__ float np_pairwise256_sq(F ld) {
    float S[2];
    #pragma unroll
    for (int h = 0; h < 2; h++) {
        int base = h * 128;
        float v[16];
        #pragma unroll
        for (int l = 0; l < 16; l++) {
            float q[8];
            #pragma unroll
            for (int j = 0; j < 8; j++) { float x = ld(base + j * 16 + l); q[j] = x * x; }
            v[l] = ((q[0] + q[1]) + (q[2] + q[3])) + ((q[4] + q[5]) + (q[6] + q[7]));
        }
        float t1[8], t2[4], t3[2];
        #pragma unroll
        for (int l = 0; l < 8; l++) t1[l] = v[l] + v[l + 8];
        #pragma unroll
        for (int l = 0; l < 4; l++) t2[l] = t1[l] + t1[l + 4];
        t3[0] = t2[0] + t2[2]; t3[1] = t2[1] + t2[3];
        S[h] = t3[0] + t3[1];
    }
    return S[0] + S[1];
}

__global__ void k_c2pw(const float* __restrict__ cb, float* __restrict__ c2) {
    int k = blockIdx.x * 256 + threadIdx.x;
    const float* row = cb + (size_t)k * D;
    c2[k] = np_pairwise256_sq([&](int d) { return row[d]; });
}

__global__ void k_z2pw(const float* __restrict__ z, float* __restrict__ z2) {
    int n = blockIdx.x * 256 + threadIdx.x;
    int b = n >> 11, t = n & 2047;
    const float* base = z + (size_t)b * CH * T + t;
    z2[n] = np_pairwise256_sq([&](int d) { return base[(size_t)d * T]; });
}

// ---- exact-fp32 GEMM-argmin: e = sequential fmaf chain over d (BLAS order),
//      s = (z2 - 2*e) + c2, strict < with first-index tie-break ----
__global__ __launch_bounds__(256) void k_exact(
        const float* __restrict__ z, const float* __restrict__ cb,
        const float* __restrict__ c2, const float* __restrict__ z2,
        float2* __restrict__ part) {
    __shared__ float zs[D][MT];       // 32 KB
    __shared__ float cs[DC][KT + 4];  // 16.9 KB

    const int tid = threadIdx.x;
    const int tx = tid & 31;          // 4 consecutive k
    const int ty = tid >> 5;          // 4 consecutive rows
    const int n0 = blockIdx.x * MT;
    const int bb = n0 >> 11;
    const int t0 = n0 & 2047;
    const int kbase = blockIdx.y * (K / NSPLIT);

    for (int i = tid; i < D * (MT / 4); i += 256) {
        int d = i >> 3, tg = i & 7;
        float4 v = *(const float4*)(z + ((size_t)(bb * CH + d)) * T + t0 + tg * 4);
        *(float4*)&zs[d][tg * 4] = v;
    }

    float z2r[4];
    #pragma unroll
    for (int i = 0; i < 4; i++) z2r[i] = z2[n0 + ty * 4 + i];

    float m1[4]; int bi[4];
    #pragma unroll
    for (int i = 0; i < 4; i++) { m1[i] = FLT_MAX; bi[i] = 0x7fffffff; }

    for (int kt = 0; kt < K / NSPLIT; kt += KT) {
        const int k0 = kbase + kt;
        float acc[4][4] = {};
        for (int dc = 0; dc < D; dc += DC) {
            __syncthreads();
            {
                int kl = tid & 127;
                int half = tid >> 7;
                const float4* src = (const float4*)(cb + (size_t)(k0 + kl) * D + dc + half * 16);
                #pragma unroll
                for (int j = 0; j < 4; j++) {
                    float4 v = src[j];
                    int dl = half * 16 + j * 4;
                    cs[dl + 0][kl] = v.x; cs[dl + 1][kl] = v.y;
                    cs[dl + 2][kl] = v.z; cs[dl + 3][kl] = v.w;
                }
            }
            __syncthreads();
            // d ascending, one fmaf per element per d: bit-exact BLAS k-chain
            #pragma unroll 8
            for (int d = 0; d < DC; d++) {
                const float4 zf = *(const float4*)&zs[dc + d][ty * 4];
                const float4 cf = *(const float4*)&cs[d][tx * 4];
                const float za[4] = {zf.x, zf.y, zf.z, zf.w};
                const float ca[4] = {cf.x, cf.y, cf.z, cf.w};
                #pragma unroll
                for (int i = 0; i < 4; i++)
                    #pragma unroll
                    for (int j = 0; j < 4; j++)
                        acc[i][j] = fmaf(za[i], ca[j], acc[i][j]);
            }
        }
        #pragma unroll
        for (int j = 0; j < 4; j++) {
            int kk = k0 + tx * 4 + j;
            float c2v = c2[kk];
            #pragma unroll
            for (int i = 0; i < 4; i++) {
                float tpre = z2r[i] - 2.0f * acc[i][j];  // np: (z2 - 2e), rounds
                float s = tpre + c2v;                    // np: + c2, rounds
                if (s < m1[i]) { m1[i] = s; bi[i] = kk; }  // strict <: first idx
            }
        }
    }

    __syncthreads();
    float* rm1 = (float*)zs;
    int*   ri  = (int*)(rm1 + MT * 32);
    #pragma unroll
    for (int i = 0; i < 4; i++) {
        int slot = (ty * 4 + i) * 32 + tx;
        rm1[slot] = m1[i]; ri[slot] = bi[i];
    }
    __syncthreads();
    if (tid < MT) {
        float a1 = FLT_MAX; int ai = 0x7fffffff;
        for (int t = 0; t < 32; t++) {
            float b1 = rm1[tid * 32 + t]; int bidx = ri[tid * 32 + t];
            if (b1 < a1 || (b1 == a1 && bidx < ai)) { a1 = b1; ai = bidx; }
        }
        part[(size_t)(n0 + tid) * NSPLIT + blockIdx.y] = make_float2(a1, __int_as_float(ai));
    }
}

__global__ void k_reduce(const float2* __restrict__ part, int* __restrict__ widx,
                         float* __restrict__ out) {
    int n = blockIdx.x * 256 + threadIdx.x;
    float a1 = FLT_MAX; int ai = 0x7fffffff;
    #pragma unroll
    for (int s = 0; s < NSPLIT; s++) {
        float2 p = part[(size_t)n * NSPLIT + s];
        float b1 = p.x; int bidx = __float_as_int(p.y);
        if (b1 < a1 || (b1 == a1 && bidx < ai)) { a1 = b1; ai = bidx; }
    }
    widx[n] = ai;
    out[OFF_IDX + n] = (float)ai;
}

// ------------- epilogue: gather z_q into z_out[:, :256, :] + loss partials ---
__global__ __launch_bounds__(256) void k_episem(
        const float* __restrict__ z, const float* __restrict__ cb,
        const int* __restrict__ widx, float* __restrict__ out, double* __restrict__ lossp) {
    __shared__ int qidx[32];
    __shared__ float qs[32][260];
    __shared__ double wsum[4];
    const int tid = threadIdx.x;
    const int bb = blockIdx.x >> 6;
    const int t0 = (blockIdx.x & 63) * 32;
    if (tid < 32) qidx[tid] = widx[bb * T + t0 + tid];
    __syncthreads();
    for (int i = tid; i < 32 * 64; i += 256) {
        int tl = i >> 6, lane = i & 63;
        float4 v = *(const float4*)(cb + (size_t)qidx[tl] * D + lane * 4);
        *(float4*)&qs[tl][lane * 4] = v;
    }
    __syncthreads();
    double ls = 0.0;
    for (int it = 0; it < 32; it++) {
        int d = it * 8 + (tid >> 5);
        int tl = tid & 31;
        size_t ga = ((size_t)(bb * CH + d)) * T + t0 + tl;
        float q = qs[tl][d];
        float e = q - z[ga];
        out[ga] = q;
        ls += (double)e * (double)e;
    }
    #pragma unroll
    for (int off = 32; off; off >>= 1) ls += __shfl_down(ls, off, 64);
    if ((tid & 63) == 0) wsum[tid >> 6] = ls;
    __syncthreads();
    if (tid == 0) lossp[blockIdx.x] = wsum[0] + wsum[1] + wsum[2] + wsum[3];
}

// ------------- epilogue: ac path; t = f32(tanh_f64(x)) ~ correctly-rounded ---
__global__ void k_epiac(const float* __restrict__ z, float* __restrict__ out) {
    int i = (blockIdx.x * 256 + threadIdx.x) * 4;
    if (i >= BQ * DAC * T) return;
    int b = i / (DAC * T);
    int r = i % (DAC * T);
    int d = r / T, t = r % T;
    size_t zoff = ((size_t)(b * CH + 256 + d)) * T + t;
    float4 v = *(const float4*)(z + zoff);
    float r0, r1, r2, r3;
    {
        float t0 = (float)tanh((double)v.x); r0 = rintf(t0 * 10.0f);
        float t1 = (float)tanh((double)v.y); r1 = rintf(t1 * 10.0f);
        float t2 = (float)tanh((double)v.z); r2 = rintf(t2 * 10.0f);
        float t3 = (float)tanh((double)v.w); r3 = rintf(t3 * 10.0f);
    }
    *(float4*)(out + zoff) = make_float4(r0, r1, r2, r3);
    size_t co = OFF_CODES + (size_t)(b * DAC + d) * T + t;
    *(float4*)(out + co) = make_float4(r0 + 10.0f, r1 + 10.0f, r2 + 10.0f, r3 + 10.0f);
    size_t ao = OFF_ACQ + (size_t)(b * DAC + d) * T + t;  // odd base: scalar stores
    out[ao + 0] = r0; out[ao + 1] = r1; out[ao + 2] = r2; out[ao + 3] = r3;
}

__global__ void k_lossfin(const double* __restrict__ lossp, float* __restrict__ out) {
    __shared__ double sm[256];
    int tid = threadIdx.x;
    sm[tid] = lossp[tid] + lossp[tid + 256];
    __syncthreads();
    for (int off = 128; off; off >>= 1) {
        if (tid < off) sm[tid] += sm[tid + off];
        __syncthreads();
    }
    if (tid == 0) out[OFF_LOSS] = (float)(1.1 * sm[0] / (double)(BQ * D * T));
}

extern "C" void kernel_launch(void* const* d_in, const int* in_sizes, int n_in,
                              void* d_out, int out_size, void* d_ws, size_t ws_size,
                              hipStream_t stream) {
    const float* z  = (const float*)d_in[0];
    const float* cb = (const float*)d_in[1];
    float* out = (float*)d_out;
    char* ws = (char*)d_ws;
    float*  c2    = (float*)(ws + WS_C2);
    float*  z2    = (float*)(ws + WS_Z2);
    float2* part  = (float2*)(ws + WS_PART);
    int*    widx  = (int*)(ws + WS_IDX);
    double* lossp = (double*)(ws + WS_LOSS);

    hipLaunchKernelGGL(k_c2pw,   dim3(K / 256),            dim3(256), 0, stream, cb, c2);
    hipLaunchKernelGGL(k_z2pw,   dim3(NROWS / 256),        dim3(256), 0, stream, z, z2);
    hipLaunchKernelGGL(k_exact,  dim3(NROWS / MT, NSPLIT), dim3(256), 0, stream, z, cb, c2, z2, part);
    hipLaunchKernelGGL(k_reduce, dim3(NROWS / 256),        dim3(256), 0, stream, part, widx, out);
    hipLaunchKernelGGL(k_episem, dim3(BQ * (T / 32)),      dim3(256), 0, stream, z, cb, widx, out, lossp);
    hipLaunchKernelGGL(k_epiac,  dim3(BQ * DAC * T / 1024), dim3(256), 0, stream, z, out);
    hipLaunchKernelGGL(k_lossfin, dim3(1),                 dim3(256), 0, stream, lossp, out);
}